// Round 10
// baseline (110.394 us; speedup 1.0000x reference)
//
#include <hip/hip_runtime.h>
#include <hip/hip_bf16.h>

typedef float f32x4 __attribute__((ext_vector_type(4)));
typedef short s16x8 __attribute__((ext_vector_type(8)));
typedef unsigned int u32;
typedef u32 u32x2 __attribute__((ext_vector_type(2)));

#define DIST_SCALE 25.0f

__device__ __forceinline__ unsigned short f2b(float f) {
  union { float f; unsigned u; } v; v.f = f;
  unsigned r = v.u + 0x7fffu + ((v.u >> 16) & 1u);
  return (unsigned short)(r >> 16);
}

__device__ __forceinline__ u32 cvtpk(float lo, float hi) {
  u32 r;
  asm("v_cvt_pk_bf16_f32 %0, %1, %2" : "=v"(r) : "v"(lo), "v"(hi));
  return r;
}

// HA: [64 samples][128 ch] bf16, 256B rows, XOR-swizzled
__device__ __forceinline__ int swzH(int s, int chbyte) {
  return (s * 256 + chbyte) ^ ((s & 7) << 4);
}

__global__ void prep_weights(const float* __restrict__ W1, const float* __restrict__ W2,
                             const float* __restrict__ W3, unsigned short* __restrict__ ws) {
  int t = blockIdx.x * 256 + threadIdx.x;
  int stride = gridDim.x * 256;
  // W1aT[n][k] (k padded 27->32 with ZEROS)
  for (int i = t; i < 128 * 32; i += stride) {
    int n = i >> 5, k = i & 31;
    ws[i] = (k < 27) ? f2b(W1[k * 128 + n]) : (unsigned short)0;
  }
  unsigned short* w2t = ws + 4096;
  for (int i = t; i < 128 * 128; i += stride) {
    int n = i >> 7, k = i & 127;
    w2t[i] = f2b(W2[k * 128 + n]);
  }
  // W3P[wv(8)][n(16)][kslot(32)]: k-slot (kg,j): j<4 -> ch = wv*16 + kg*4 + j, j>=4 -> zero
  unsigned short* w3p = ws + 4096 + 16384;
  for (int i = t; i < 8 * 16 * 32; i += stride) {
    int wv = i >> 9, rem = i & 511, n = rem >> 5, ks = rem & 31;
    int kg = ks >> 3, j = ks & 7;
    int ch = wv * 16 + kg * 4 + (j & 3);
    w3p[i] = (n < 3 && j < 4) ? f2b(W3[ch * 3 + n]) : (unsigned short)0;
  }
}

__global__ void __launch_bounds__(512, 6) nerf_main(
    const float* __restrict__ dens, const float* __restrict__ app,
    const float* __restrict__ vdirs, const float* __restrict__ dists,
    const float* __restrict__ W1, const float* __restrict__ b1,
    const float* __restrict__ b2v, const float* __restrict__ b3v,
    const unsigned short* __restrict__ wsb, float* __restrict__ out) {
  __shared__ unsigned short Xs[64 * 40];      // 5 KB bf16 X [s][k pad 27->40], 80B rows
  __shared__ unsigned short HA[64 * 128];     // 16 KB H1 activations [s][ch]
  __shared__ float part[8 * 4 * 16 * 4];      // 8 KB partial C3 [srcwave][tile][cl][4]
  __shared__ float wbuf[256];
  __shared__ float hcbuf[128];
  __shared__ float featbuf[40];
  __shared__ float red[4][4];

  const int t = threadIdx.x;
  const int lane = t & 63;
  const int wv = t >> 6;        // 0..7
  const int r = blockIdx.x;

  const unsigned short* W1aT = wsb;
  const unsigned short* W2T = wsb + 4096;
  const unsigned short* W3P = wsb + 4096 + 16384;
  char* HAb = (char*)HA;

  const int cl = lane & 15;     // A/C column index (sample-in-tile)
  const int kg = lane >> 4;     // k-group; C rows = kg*4+i
  const int ch16 = wv * 16;     // this wave's output-channel slice

  const float* rayBase = app + (size_t)r * 6912;

  // ---------------- prologue ----------------
  // zero Xs once (pad cols 27..39 stay zero; scatter only rewrites cols 0..26)
  for (int i = t; i < 1280; i += 512) ((u32*)Xs)[i] = 0u;
  if (t < 39) {   // view-dir features: [vd(3), sin(18), cos(18)]
    float val;
    if (t < 3) val = vdirs[r * 3 + t];
    else {
      int jj = t - 3;
      int trig = jj / 18;
      int rem = jj % 18;
      int c = rem / 6, k = rem % 6;
      float v = vdirs[r * 3 + c] * (float)(1 << k);
      val = trig ? cosf(v) : sinf(v);
    }
    featbuf[t] = val;
  }
  // transmittance/weight scan (wave 0, 4 samples/lane)
  if (wv == 0) {
    const float4 dv = *(const float4*)(dens + (size_t)r * 256 + lane * 4);
    const float4 tv = *(const float4*)(dists + (size_t)r * 256 + lane * 4);
    float f[4], al[4];
    float dl[4] = {dv.x, dv.y, dv.z, dv.w};
    float tl[4] = {tv.x, tv.y, tv.z, tv.w};
    float p = 1.0f;
#pragma unroll
    for (int q = 0; q < 4; ++q) {
      float sg = fmaxf(dl[q], 0.0f);
      float e = __expf(-sg * tl[q] * DIST_SCALE);
      al[q] = 1.0f - e;
      f[q] = e + 1e-10f;
      p *= f[q];
    }
    float P = p;
#pragma unroll
    for (int dlt = 1; dlt < 64; dlt <<= 1) {
      float v = __shfl_up(P, dlt, 64);
      if (lane >= dlt) P *= v;
    }
    float E = __shfl_up(P, 1, 64);
    if (lane == 0) E = 1.0f;
    float tr = E;
#pragma unroll
    for (int q = 0; q < 4; ++q) { wbuf[lane * 4 + q] = al[q] * tr; tr *= f[q]; }
  }
  __syncthreads();
  // per-ray folded layer-1 bias: h1c = b1 + vd_feats @ W1[27:66]
  if (t < 128) {
    float s = b1[t];
    for (int j = 0; j < 39; ++j) s += featbuf[j] * W1[(27 + j) * 128 + t];
    hcbuf[t] = s;
  }

  // ---- hoist this wave's weight slice into registers (one-time, 24 VGPR) ----
  s16x8 w1f, w2f[4], w3s;
  w1f = *(const s16x8*)(W1aT + (ch16 + cl) * 32 + kg * 8);
#pragma unroll
  for (int kk = 0; kk < 4; ++kk)
    w2f[kk] = *(const s16x8*)(W2T + (ch16 + cl) * 128 + kk * 32 + kg * 8);
  w3s = *(const s16x8*)(W3P + wv * 512 + cl * 32 + kg * 8);

  const f32x4 bb0 = *(const f32x4*)(b2v + ch16 + kg * 4);
  const float b30 = b3v[0], b31 = b3v[1], b32 = b3v[2];
  float pr = 0.0f, pg = 0.0f, pb = 0.0f, pw = 0.0f;

  __syncthreads();   // hcbuf ready
  const f32x4 hc0 = *(const f32x4*)(hcbuf + ch16 + kg * 4);

  // ---- preload chunk 0 staging into registers (432 threads x f32x4, coalesced) ----
  f32x4 L0 = {};
  if (t < 432) L0 = *(const f32x4*)(rayBase + 4 * t);

  for (int chunk = 0; chunk < 4; ++chunk) {
    // ---- commit prefetched X: f32 regs -> bf16 scatter into Xs[s][c] ----
    if (t < 432) {
      int e0 = 4 * t;
#pragma unroll
      for (int u = 0; u < 4; ++u) {
        unsigned e = e0 + u;
        unsigned s = e / 27u, c = e - s * 27u;
        *(unsigned short*)((char*)Xs + s * 80 + 2 * c) = f2b(L0[u]);
      }
    }
    __syncthreads();   // B1: Xs staged

    // ---- prefetch next chunk into regs (hides under L1..L3 compute) ----
    if (chunk < 3 && t < 432)
      L0 = *(const f32x4*)(rayBase + (size_t)(chunk + 1) * 1728 + 4 * t);

    // ---- layer 1 (per sample-tile; ONE ds_read_b128 B-frag) ----
#pragma unroll
    for (int st = 0; st < 4; ++st) {
      const int s = st * 16 + cl;
      s16x8 xb = *(const s16x8*)((char*)Xs + s * 80 + kg * 16);
      f32x4 a0 = {};
      a0 = __builtin_amdgcn_mfma_f32_16x16x32_bf16(w1f, xb, a0, 0, 0, 0);
      u32x2 pk0 = {cvtpk(fmaxf(a0[0] + hc0[0], 0.0f), fmaxf(a0[1] + hc0[1], 0.0f)),
                   cvtpk(fmaxf(a0[2] + hc0[2], 0.0f), fmaxf(a0[3] + hc0[3], 0.0f))};
      *(u32x2*)(HAb + swzH(s, (ch16 + kg * 4) * 2)) = pk0;
    }
    __syncthreads();   // B2: H1 complete; all Xs reads done

    // ---- layer 2 + fused layer-3 partial (B3 = own relu'd acc regs, W3P-permuted) ----
#pragma unroll
    for (int st = 0; st < 4; ++st) {
      const int s = st * 16 + cl;
      f32x4 a0 = {};
      {
        s16x8 h0 = *(const s16x8*)(HAb + swzH(s, (0 * 32 + kg * 8) * 2));
        s16x8 h1 = *(const s16x8*)(HAb + swzH(s, (1 * 32 + kg * 8) * 2));
        a0 = __builtin_amdgcn_mfma_f32_16x16x32_bf16(w2f[0], h0, a0, 0, 0, 0);
        a0 = __builtin_amdgcn_mfma_f32_16x16x32_bf16(w2f[1], h1, a0, 0, 0, 0);
        h0 = *(const s16x8*)(HAb + swzH(s, (2 * 32 + kg * 8) * 2));
        h1 = *(const s16x8*)(HAb + swzH(s, (3 * 32 + kg * 8) * 2));
        a0 = __builtin_amdgcn_mfma_f32_16x16x32_bf16(w2f[2], h0, a0, 0, 0, 0);
        a0 = __builtin_amdgcn_mfma_f32_16x16x32_bf16(w2f[3], h1, a0, 0, 0, 0);
      }
      union { u32 u[4]; s16x8 v; } b3;
      b3.u[0] = cvtpk(fmaxf(a0[0] + bb0[0], 0.0f), fmaxf(a0[1] + bb0[1], 0.0f));
      b3.u[1] = cvtpk(fmaxf(a0[2] + bb0[2], 0.0f), fmaxf(a0[3] + bb0[3], 0.0f));
      b3.u[2] = 0u;
      b3.u[3] = 0u;
      f32x4 p3 = {};
      p3 = __builtin_amdgcn_mfma_f32_16x16x32_bf16(w3s, b3.v, p3, 0, 0, 0);
      if (kg == 0)   // rgb rows 0..2 of this wave's 16-ch K-partial
        *(f32x4*)(part + ((wv * 4 + st) * 16 + cl) * 4) = p3;
    }
    __syncthreads();   // B3: partials written

    // ---- cross-wave K-reduction of C3 partials + composite (waves 0..3, tile=wv) ----
    if (wv < 4) {
      f32x4 pa = *(const f32x4*)(part + ((kg * 4 + wv) * 16 + cl) * 4);
      f32x4 pb4 = *(const f32x4*)(part + (((kg + 4) * 4 + wv) * 16 + cl) * 4);
      float v0 = pa[0] + pb4[0];
      float v1 = pa[1] + pb4[1];
      float v2 = pa[2] + pb4[2];
      v0 += __shfl_xor(v0, 16, 64); v0 += __shfl_xor(v0, 32, 64);
      v1 += __shfl_xor(v1, 16, 64); v1 += __shfl_xor(v1, 32, 64);
      v2 += __shfl_xor(v2, 16, 64); v2 += __shfl_xor(v2, 32, 64);
      if (kg == 0) {
        float w = wbuf[chunk * 64 + wv * 16 + cl];
        pw += w;
        pr += w / (1.0f + __expf(-(v0 + b30)));
        pg += w / (1.0f + __expf(-(v1 + b31)));
        pb += w / (1.0f + __expf(-(v2 + b32)));
      }
    }
    // loop: next commit (Xs writes) is fenced from this chunk's Xs reads by B2+B3;
    // next HA writes fenced from this chunk's HA reads by B3+next B1;
    // next part writes fenced from these part reads by next B1+B2
  }

  // ---------------- final reduce + composite ----------------
  if (wv < 4 && kg == 0) {
#pragma unroll
    for (int d = 1; d < 16; d <<= 1) {
      pr += __shfl_xor(pr, d, 64);
      pg += __shfl_xor(pg, d, 64);
      pb += __shfl_xor(pb, d, 64);
      pw += __shfl_xor(pw, d, 64);
    }
    if (lane == 0) { red[wv][0] = pr; red[wv][1] = pg; red[wv][2] = pb; red[wv][3] = pw; }
  }
  __syncthreads();
  if (t == 0) {
    float R = 0, G = 0, B = 0, W = 0;
#pragma unroll
    for (int w = 0; w < 4; ++w) { R += red[w][0]; G += red[w][1]; B += red[w][2]; W += red[w][3]; }
    float bg = 1.0f - W;
    out[r * 3 + 0] = fminf(fmaxf(R + bg, 0.0f), 1.0f);
    out[r * 3 + 1] = fminf(fmaxf(G + bg, 0.0f), 1.0f);
    out[r * 3 + 2] = fminf(fmaxf(B + bg, 0.0f), 1.0f);
  }
}

extern "C" void kernel_launch(void* const* d_in, const int* in_sizes, int n_in,
                              void* d_out, int out_size, void* d_ws, size_t ws_size,
                              hipStream_t stream) {
  const float* dens = (const float*)d_in[0];
  const float* app  = (const float*)d_in[1];
  const float* vd   = (const float*)d_in[2];
  const float* dist = (const float*)d_in[3];
  const float* W1   = (const float*)d_in[4];
  const float* b1   = (const float*)d_in[5];
  const float* W2   = (const float*)d_in[6];
  const float* b2   = (const float*)d_in[7];
  const float* W3   = (const float*)d_in[8];
  const float* b3   = (const float*)d_in[9];
  unsigned short* wsb = (unsigned short*)d_ws;

  prep_weights<<<32, 256, 0, stream>>>(W1, W2, W3, wsb);
  nerf_main<<<4096, 512, 0, stream>>>(dens, app, vd, dist, W1, b1, b2, b3, wsb, (float*)d_out);
}

// Round 11
// 79.416 us; speedup vs baseline: 1.3901x; 1.3901x over previous
//
#include <hip/hip_runtime.h>
#include <hip/hip_bf16.h>

typedef float f32x4 __attribute__((ext_vector_type(4)));
typedef short s16x8 __attribute__((ext_vector_type(8)));
typedef unsigned int u32;
typedef u32 u32x2 __attribute__((ext_vector_type(2)));

#define DIST_SCALE 25.0f

__device__ __forceinline__ unsigned short f2b(float f) {
  union { float f; unsigned u; } v; v.f = f;
  unsigned r = v.u + 0x7fffu + ((v.u >> 16) & 1u);
  return (unsigned short)(r >> 16);
}

__device__ __forceinline__ u32 cvtpk(float lo, float hi) {
  u32 r;
  asm("v_cvt_pk_bf16_f32 %0, %1, %2" : "=v"(r) : "v"(lo), "v"(hi));
  return r;
}

// HA: [64 samples][128 ch] bf16, 256B rows, XOR-swizzled
__device__ __forceinline__ int swzH(int s, int chbyte) {
  return (s * 256 + chbyte) ^ ((s & 7) << 4);
}

__global__ void prep_weights(const float* __restrict__ W1, const float* __restrict__ W2,
                             const float* __restrict__ W3, unsigned short* __restrict__ ws) {
  int t = blockIdx.x * 256 + threadIdx.x;
  int stride = gridDim.x * 256;
  // W1aT[n][k] (k padded 27->32 with ZEROS - annihilates X pad garbage)
  for (int i = t; i < 128 * 32; i += stride) {
    int n = i >> 5, k = i & 31;
    ws[i] = (k < 27) ? f2b(W1[k * 128 + n]) : (unsigned short)0;
  }
  unsigned short* w2t = ws + 4096;
  for (int i = t; i < 128 * 128; i += stride) {
    int n = i >> 7, k = i & 127;
    w2t[i] = f2b(W2[k * 128 + n]);
  }
  // W3P[wv(4)][n(16)][kslot(32)]: k-slot (kg,j) -> ch = wv*32 + 16*(j>>2) + kg*4 + (j&3)
  // (matches the in-register k-packing of each wave's L2 accumulator)
  unsigned short* w3p = ws + 4096 + 16384;
  for (int i = t; i < 4 * 16 * 32; i += stride) {
    int wv = i >> 9, rem = i & 511, n = rem >> 5, ks = rem & 31;
    int kg = ks >> 3, j = ks & 7;
    int ch = wv * 32 + ((j >> 2) << 4) + kg * 4 + (j & 3);
    w3p[i] = (n < 3) ? f2b(W3[ch * 3 + n]) : (unsigned short)0;
  }
}

__global__ void __launch_bounds__(256, 3) nerf_main(
    const float* __restrict__ dens, const float* __restrict__ app,
    const float* __restrict__ vdirs, const float* __restrict__ dists,
    const float* __restrict__ W1, const float* __restrict__ b1,
    const float* __restrict__ b2v, const float* __restrict__ b3v,
    const unsigned short* __restrict__ wsb, float* __restrict__ out) {
  __shared__ unsigned short Xs[64 * 40];      // 5 KB bf16 X, [s][k pad 27->40], 80B rows
  __shared__ unsigned short HA[64 * 128];     // 16 KB H1 activations [s][ch]
  __shared__ float part[4 * 4 * 16 * 4];      // 4 KB partial C3 [srcwave][tile][cl][4]
  __shared__ float wbuf[256];
  __shared__ float hcbuf[128];
  __shared__ float featbuf[40];
  __shared__ float red[4][4];

  const int t = threadIdx.x;
  const int lane = t & 63;
  const int wv = t >> 6;
  const int r = blockIdx.x;

  const unsigned short* W1aT = wsb;
  const unsigned short* W2T = wsb + 4096;
  const unsigned short* W3P = wsb + 4096 + 16384;
  char* HAb = (char*)HA;

  const int cl = lane & 15;    // A-row / C-col index
  const int kg = lane >> 4;    // k-group; C rows = kg*4+i
  const int chBase = wv * 32;  // this wave's output-channel slice

  // ---------------- prologue ----------------
  // zero Xs once (pad cols 27..39 stay zero; stage only rewrites cols 0..26)
  for (int i = t; i < 1280; i += 256) ((u32*)Xs)[i] = 0u;
  if (t < 39) {   // view-dir features: [vd(3), sin(18), cos(18)]
    float val;
    if (t < 3) val = vdirs[r * 3 + t];
    else {
      int jj = t - 3;
      int trig = jj / 18;
      int rem = jj % 18;
      int c = rem / 6, k = rem % 6;
      float v = vdirs[r * 3 + c] * (float)(1 << k);
      val = trig ? cosf(v) : sinf(v);
    }
    featbuf[t] = val;
  }
  // transmittance/weight scan (wave 0, 4 samples/lane)
  if (wv == 0) {
    const float4 dv = *(const float4*)(dens + (size_t)r * 256 + lane * 4);
    const float4 tv = *(const float4*)(dists + (size_t)r * 256 + lane * 4);
    float f[4], al[4];
    float dl[4] = {dv.x, dv.y, dv.z, dv.w};
    float tl[4] = {tv.x, tv.y, tv.z, tv.w};
    float p = 1.0f;
#pragma unroll
    for (int q = 0; q < 4; ++q) {
      float sg = fmaxf(dl[q], 0.0f);
      float e = __expf(-sg * tl[q] * DIST_SCALE);
      al[q] = 1.0f - e;
      f[q] = e + 1e-10f;
      p *= f[q];
    }
    float P = p;
#pragma unroll
    for (int dlt = 1; dlt < 64; dlt <<= 1) {
      float v = __shfl_up(P, dlt, 64);
      if (lane >= dlt) P *= v;
    }
    float E = __shfl_up(P, 1, 64);
    if (lane == 0) E = 1.0f;
    float tr = E;
#pragma unroll
    for (int q = 0; q < 4; ++q) { wbuf[lane * 4 + q] = al[q] * tr; tr *= f[q]; }
  }
  __syncthreads();
  // per-ray folded layer-1 bias: h1c = b1 + vd_feats @ W1[27:66]
  if (t < 128) {
    float s = b1[t];
    for (int j = 0; j < 39; ++j) s += featbuf[j] * W1[(27 + j) * 128 + t];
    hcbuf[t] = s;
  }

  // ---- hoist this wave's weight slice into registers (one-time, 44 VGPR) ----
  s16x8 w1f[2], w2f[2][4], w3s;
#pragma unroll
  for (int nt = 0; nt < 2; ++nt)
    w1f[nt] = *(const s16x8*)(W1aT + (chBase + nt * 16 + cl) * 32 + kg * 8);
#pragma unroll
  for (int nt = 0; nt < 2; ++nt)
#pragma unroll
    for (int kk = 0; kk < 4; ++kk)
      w2f[nt][kk] = *(const s16x8*)(W2T + (chBase + nt * 16 + cl) * 128 + kk * 32 + kg * 8);
  w3s = *(const s16x8*)(W3P + wv * 512 + cl * 32 + kg * 8);

  __syncthreads();

  float pr = 0.0f, pg = 0.0f, pb = 0.0f, pw = 0.0f;
  const float b30 = b3v[0], b31 = b3v[1], b32 = b3v[2];
  // chunk-invariant epilogue constants
  const f32x4 hc0 = *(const f32x4*)(hcbuf + chBase + kg * 4);
  const f32x4 hc1 = *(const f32x4*)(hcbuf + chBase + 16 + kg * 4);
  const f32x4 bb0 = *(const f32x4*)(b2v + chBase + kg * 4);
  const f32x4 bb1 = *(const f32x4*)(b2v + chBase + 16 + kg * 4);

  // ---- preload chunk 0 staging into registers (block-linear, coalesced) ----
  const float* rayBase = app + (size_t)r * 256 * 27;
  f32x4 L0 = *(const f32x4*)(rayBase + 4 * t);
  f32x4 L1 = {};
  if (t < 176) L1 = *(const f32x4*)(rayBase + 4 * (t + 256));

  for (int chunk = 0; chunk < 4; ++chunk) {
    const int sBase = chunk * 64;
    // ---- commit prefetched X: f32 regs -> bf16 scatter into Xs[s][c] ----
    {
      int e0 = 4 * t;
#pragma unroll
      for (int u = 0; u < 4; ++u) {
        unsigned e = e0 + u;
        unsigned s = e / 27u, c = e - s * 27u;
        *(unsigned short*)((char*)Xs + s * 80 + 2 * c) = f2b(L0[u]);
      }
      if (t < 176) {
        int e1 = 4 * (t + 256);
#pragma unroll
        for (int u = 0; u < 4; ++u) {
          unsigned e = e1 + u;
          unsigned s = e / 27u, c = e - s * 27u;
          *(unsigned short*)((char*)Xs + s * 80 + 2 * c) = f2b(L1[u]);
        }
      }
    }
    __syncthreads();   // B1: Xs ready (also fences prev-chunk HA/part reads)

    // ---- prefetch next chunk into regs (latency hides under L1+L2 compute) ----
    if (chunk < 3) {
      const float* slab = rayBase + (size_t)(chunk + 1) * 1728;
      L0 = *(const f32x4*)(slab + 4 * t);
      if (t < 176) L1 = *(const f32x4*)(slab + 4 * (t + 256));
    }

    // ---- layer 1 (streamed per sample-tile; one ds_read_b128 B-frag) ----
#pragma unroll
    for (int st = 0; st < 4; ++st) {
      const int s = st * 16 + cl;
      s16x8 xb = *(const s16x8*)((char*)Xs + s * 80 + kg * 16);
      f32x4 a0 = {}, a1 = {};
      a0 = __builtin_amdgcn_mfma_f32_16x16x32_bf16(w1f[0], xb, a0, 0, 0, 0);
      a1 = __builtin_amdgcn_mfma_f32_16x16x32_bf16(w1f[1], xb, a1, 0, 0, 0);
      u32x2 pk0 = {cvtpk(fmaxf(a0[0] + hc0[0], 0.0f), fmaxf(a0[1] + hc0[1], 0.0f)),
                   cvtpk(fmaxf(a0[2] + hc0[2], 0.0f), fmaxf(a0[3] + hc0[3], 0.0f))};
      u32x2 pk1 = {cvtpk(fmaxf(a1[0] + hc1[0], 0.0f), fmaxf(a1[1] + hc1[1], 0.0f)),
                   cvtpk(fmaxf(a1[2] + hc1[2], 0.0f), fmaxf(a1[3] + hc1[3], 0.0f))};
      *(u32x2*)(HAb + swzH(s, (chBase + kg * 4) * 2)) = pk0;
      *(u32x2*)(HAb + swzH(s, (chBase + 16 + kg * 4) * 2)) = pk1;
    }
    __syncthreads();   // B2: H1 complete; all Xs reads done

    // ---- layer 2 + fused layer-3 partial (B3 = own relu'd acc2 regs, W3P-permuted) ----
#pragma unroll
    for (int st = 0; st < 4; ++st) {
      const int s = st * 16 + cl;
      s16x8 hbf[4];
#pragma unroll
      for (int kk = 0; kk < 4; ++kk)
        hbf[kk] = *(const s16x8*)(HAb + swzH(s, (kk * 32 + kg * 8) * 2));
      f32x4 a0 = {}, a1 = {};
#pragma unroll
      for (int kk = 0; kk < 4; ++kk) {
        a0 = __builtin_amdgcn_mfma_f32_16x16x32_bf16(w2f[0][kk], hbf[kk], a0, 0, 0, 0);
        a1 = __builtin_amdgcn_mfma_f32_16x16x32_bf16(w2f[1][kk], hbf[kk], a1, 0, 0, 0);
      }
      // H2 slice in-register: relu(acc2 + b2), packed in k-slot order matching W3P
      union { u32 u[4]; s16x8 v; } b3;
      b3.u[0] = cvtpk(fmaxf(a0[0] + bb0[0], 0.0f), fmaxf(a0[1] + bb0[1], 0.0f));
      b3.u[1] = cvtpk(fmaxf(a0[2] + bb0[2], 0.0f), fmaxf(a0[3] + bb0[3], 0.0f));
      b3.u[2] = cvtpk(fmaxf(a1[0] + bb1[0], 0.0f), fmaxf(a1[1] + bb1[1], 0.0f));
      b3.u[3] = cvtpk(fmaxf(a1[2] + bb1[2], 0.0f), fmaxf(a1[3] + bb1[3], 0.0f));
      f32x4 p3 = {};
      p3 = __builtin_amdgcn_mfma_f32_16x16x32_bf16(w3s, b3.v, p3, 0, 0, 0);
      if (kg == 0)   // rgb rows 0..2 of this wave's K-partial
        *(f32x4*)(part + ((wv * 4 + st) * 16 + cl) * 4) = p3;
    }
    __syncthreads();   // B3: partials written

    // ---- cross-wave K-reduction of C3 partials + composite (wave wv handles tile wv) ----
    {
      f32x4 pv = *(const f32x4*)(part + ((kg * 4 + wv) * 16 + cl) * 4);
      float v0 = pv[0], v1 = pv[1], v2 = pv[2];
      v0 += __shfl_xor(v0, 16, 64); v0 += __shfl_xor(v0, 32, 64);
      v1 += __shfl_xor(v1, 16, 64); v1 += __shfl_xor(v1, 32, 64);
      v2 += __shfl_xor(v2, 16, 64); v2 += __shfl_xor(v2, 32, 64);
      if (kg == 0) {
        float w = wbuf[sBase + wv * 16 + cl];
        pw += w;
        pr += w / (1.0f + __expf(-(v0 + b30)));
        pg += w / (1.0f + __expf(-(v1 + b31)));
        pb += w / (1.0f + __expf(-(v2 + b32)));
      }
    }
    // loop back: Xs/HA rewrites are fenced by B1/B2 of the next chunk; part reads complete
    // before each wave reaches the next B2 (single buffer safe)
  }

  // ---------------- final reduce + composite ----------------
  if (kg == 0) {
#pragma unroll
    for (int d = 1; d < 16; d <<= 1) {
      pr += __shfl_xor(pr, d, 64);
      pg += __shfl_xor(pg, d, 64);
      pb += __shfl_xor(pb, d, 64);
      pw += __shfl_xor(pw, d, 64);
    }
    if (lane == 0) { red[wv][0] = pr; red[wv][1] = pg; red[wv][2] = pb; red[wv][3] = pw; }
  }
  __syncthreads();
  if (t == 0) {
    float R = 0, G = 0, B = 0, W = 0;
#pragma unroll
    for (int w = 0; w < 4; ++w) { R += red[w][0]; G += red[w][1]; B += red[w][2]; W += red[w][3]; }
    float bg = 1.0f - W;
    out[r * 3 + 0] = fminf(fmaxf(R + bg, 0.0f), 1.0f);
    out[r * 3 + 1] = fminf(fmaxf(G + bg, 0.0f), 1.0f);
    out[r * 3 + 2] = fminf(fmaxf(B + bg, 0.0f), 1.0f);
  }
}

extern "C" void kernel_launch(void* const* d_in, const int* in_sizes, int n_in,
                              void* d_out, int out_size, void* d_ws, size_t ws_size,
                              hipStream_t stream) {
  const float* dens = (const float*)d_in[0];
  const float* app  = (const float*)d_in[1];
  const float* vd   = (const float*)d_in[2];
  const float* dist = (const float*)d_in[3];
  const float* W1   = (const float*)d_in[4];
  const float* b1   = (const float*)d_in[5];
  const float* W2   = (const float*)d_in[6];
  const float* b2   = (const float*)d_in[7];
  const float* W3   = (const float*)d_in[8];
  const float* b3   = (const float*)d_in[9];
  unsigned short* wsb = (unsigned short*)d_ws;

  prep_weights<<<32, 256, 0, stream>>>(W1, W2, W3, wsb);
  nerf_main<<<4096, 256, 0, stream>>>(dens, app, vd, dist, W1, b1, b2, b3, wsb, (float*)d_out);
}